// Round 4
// baseline (5738.511 us; speedup 1.0000x reference)
//
#include <hip/hip_runtime.h>
#include <stdint.h>

typedef __attribute__((ext_vector_type(4))) float    f32x4;
typedef __attribute__((ext_vector_type(8))) short    short8;
typedef __attribute__((ext_vector_type(2))) uint32_t u32x2;

#define NTAP 27
#define C 128
#define PB 128
#define TOTAL_W (NTAP * 4 * 8 * 64 * 4)   // wpf dwords

__device__ __forceinline__ uint32_t f2bf(float f) {
    union { float f; uint32_t u; } v; v.f = f;
    uint32_t u = v.u;
    return (u + 0x7FFFu + ((u >> 16) & 1u)) >> 16;  // RNE
}

// ---------------- prep kernels ----------------

__global__ void k_codes(const int* __restrict__ pts, int* __restrict__ codes, int n, int r) {
    int i = blockIdx.x * blockDim.x + threadIdx.x;
    if (i < n) codes[i] = (pts[i*3] * r + pts[i*3+1]) * r + pts[i*3+2];
}

// merged: W -> MFMA-B-fragment order (bf16 pairs) + code->idx table fill
__global__ void k_prep(const float* __restrict__ w, uint32_t* __restrict__ wpf,
                       const int* __restrict__ pts, int* __restrict__ table,
                       int n_tab, int r) {
    int i = blockIdx.x * blockDim.x + threadIdx.x;
    if (i < TOTAL_W) {
        int d = i & 3, l = (i >> 2) & 63, cb = (i >> 8) & 7, ks = (i >> 11) & 3, k = i >> 13;
        int co = (cb << 4) + (l & 15);
        int ci = (ks << 5) + ((l >> 4) << 3) + (d << 1);
        float w0 = w[((size_t)k * C + ci) * C + co];
        float w1 = w[((size_t)k * C + ci + 1) * C + co];
        wpf[i] = f2bf(w0) | (f2bf(w1) << 16);
    } else {
        int j = i - TOTAL_W;
        if (j < n_tab) {
            int code = (pts[j*3] * r + pts[j*3+1]) * r + pts[j*3+2];
            table[code] = j + 1;
        }
    }
}

// ---------------- main fused kernel ----------------
// 512 threads = 8 waves; wave w owns output cols [w*16, w*16+16).
// Pipelined worklist of (tap, mtile-of-16) chunks; A-tile double-buffered;
// raw s_barrier + counted vmcnt keeps gathers in flight across barriers.
//
// A-tile layout (conflict-free both sides): 16 slots x 256B; slot s = kappa>>3
// holds bf16 k-elements [8s, 8s+8) of all 16 rows; row r at byte
// s*256 + ((r^s)&15)*16. Reads: 16B/lane, wave covers 1024B contiguous.

template <bool USE_TABLE>
__global__ __launch_bounds__(512, 4) void k_main(
    const int* __restrict__ pts, const float* __restrict__ x,
    const uint32_t* __restrict__ wpf, const float* __restrict__ bias,
    const float* __restrict__ gamma, const float* __restrict__ beta,
    const int* __restrict__ table, const int* __restrict__ codes,
    float* __restrict__ out, int n, int r, int nwg)
{
    __shared__ uint4 abuf4[2][256];           // 2 x 4KB A tiles
    __shared__ int   jtabF[28 * PB];          // j+1 per (tap,row); row 27 = dummy zeros
    __shared__ int   anyb[28];                // per-tap mtile validity bitmask
    __shared__ unsigned short wl[232];        // worklist entries (k<<3)|mt
    __shared__ int   wtot[4], wbaseS[4], ncS[2];
    __shared__ float p1s[PB], p2s[PB];
    __shared__ float2 mr[PB];

    const int tid = threadIdx.x;
    const int w   = tid >> 6;
    const int l   = tid & 63;

    // bijective XCD-aware swizzle (consecutive logical blocks share gather locality)
    int bid = blockIdx.x;
    int q = nwg >> 3, rem = nwg & 7;
    int xcd = bid & 7, t8 = bid >> 3;
    int sb = (xcd < rem) ? (xcd * (q + 1) + t8) : (rem * (q + 1) + (xcd - rem) * q + t8);
    const int base = sb * PB;

    // ---- init ----
    for (int i = tid; i < 28 * PB; i += 512) jtabF[i] = 0;
    if (tid < 28) anyb[tid] = (tid == 13) ? 0xFF : 0;
    if (tid < PB) { p1s[tid] = 0.f; p2s[tid] = 0.f; }
    __syncthreads();

    if (tid < PB) jtabF[13 * PB + tid] = (base + tid < n) ? (base + tid + 1) : 0;

    // ---- phase 1: neighbor lookups (9 dx/dy groups x 3 adjacent z codes) ----
    for (int s = tid; s < 9 * PB; s += 512) {
        int g = s >> 7, t = s & (PB - 1);
        int gp = base + t;
        if (gp >= n) continue;
        int pa = pts[gp*3], pb = pts[gp*3+1], pc = pts[gp*3+2];
        int dx = g / 3 - 1, dy = g % 3 - 1;
        int q0 = pa + dx, q1 = pb + dy;
        if (q0 < 0 || q0 >= r || q1 < 0 || q1 >= r) continue;
        int qb = (q0 * r + q1) * r + pc;
        #pragma unroll
        for (int dz = -1; dz <= 1; ++dz) {
            int k = g * 3 + dz + 1;
            if (k == 13) continue;
            int q2 = pc + dz;
            if (q2 < 0 || q2 >= r) continue;
            int qc = qb + dz;
            int j1 = 0;
            if (USE_TABLE) {
                int v = table[qc];               // ws poison 0xAA.. is negative
                if (v >= 1 && v <= n) j1 = v;
            } else {
                int lo = 0, hi = n;
                while (lo < hi) { int mid = (lo + hi) >> 1; if (codes[mid] < qc) lo = mid + 1; else hi = mid; }
                if (lo < n && codes[lo] == qc) j1 = lo + 1;
            }
            if (j1) { jtabF[k * PB + t] = j1; atomicOr(&anyb[k], 1 << (t >> 4)); }
        }
    }
    __syncthreads();

    // ---- worklist build (order-preserving ballot compaction, waves 0-3) ----
    unsigned long long bmask = 0; bool bflag = false;
    if (tid < 256) {
        if (tid < NTAP * 8) bflag = (anyb[tid >> 3] >> (tid & 7)) & 1;
        bmask = __ballot(bflag ? 1 : 0);
        if ((tid & 63) == 0) wtot[tid >> 6] = __popcll(bmask);
    }
    __syncthreads();
    if (tid == 0) {
        int tot = 0;
        #pragma unroll
        for (int i2 = 0; i2 < 4; ++i2) { wbaseS[i2] = tot; tot += wtot[i2]; }
        ncS[0] = tot;
        ncS[1] = (tot + 1) & ~1;             // pad to even
        wl[tot] = NTAP << 3; wl[tot+1] = NTAP << 3; wl[tot+2] = NTAP << 3; wl[tot+3] = NTAP << 3;
    }
    __syncthreads();
    if (tid < 256 && bflag) {
        unsigned long long lt = bmask & ((1ull << (tid & 63)) - 1ull);
        wl[wbaseS[tid >> 6] + __popcll(lt)] = (unsigned short)tid;
    }
    __syncthreads();

    const int nc = ncS[1];

    // ---- per-thread constants ----
    const int srow = tid >> 5, sc4 = tid & 31;
    const int slot_w = sc4 >> 1;
    const int wbyte = slot_w * 256 + (((srow ^ slot_w) & 15) << 4) + ((sc4 & 1) << 3);
    const int arow = l & 15, kgrp = l >> 4;
    int rb[4];
    #pragma unroll
    for (int ks = 0; ks < 4; ++ks) { int sr = ks * 4 + kgrp; rb[ks] = sr * 256 + (((arow ^ sr) & 15) << 4); }
    char* ab0 = (char*)abuf4[0];
    char* ab1 = (char*)abuf4[1];

    float bv = bias[(w << 4) + arow];
    f32x4 acc[8];
    #pragma unroll
    for (int m2 = 0; m2 < 8; ++m2) acc[m2] = (f32x4){bv, bv, bv, bv};

    #define BLOAD(kk, ks) (*(const short8*)(wpf + (((size_t)((((kk) > 26 ? 26 : (kk)) * 4 + (ks)) * 8 + w) << 6) + l) * 4))

    // ---- prologue: B for first tap, gathers for chunks 0,1 ----
    int kC = wl[0] >> 3;
    short8 bC0 = BLOAD(kC, 0), bC1 = BLOAD(kC, 1), bC2 = BLOAD(kC, 2), bC3 = BLOAD(kC, 3);
    short8 bN0 = bC0, bN1 = bC1, bN2 = bC2, bN3 = bC3;
    f32x4 xvA, xvB; int jA, jB;
    { int e = wl[0]; int jv = jtabF[(e >> 3) * PB + (e & 7) * 16 + srow]; jA = jv;
      int j0 = jv > 0 ? jv - 1 : 0; xvA = *(const f32x4*)(x + (size_t)j0 * C + (sc4 << 2)); }
    { int e = wl[1]; int jv = jtabF[(e >> 3) * PB + (e & 7) * 16 + srow]; jB = jv;
      int j0 = jv > 0 ? jv - 1 : 0; xvB = *(const f32x4*)(x + (size_t)j0 * C + (sc4 << 2)); }
    bool isNew = false;

    #define MFMA4(ii) { \
        acc[ii] = __builtin_amdgcn_mfma_f32_16x16x32_bf16(a0, bC0, acc[ii], 0, 0, 0); \
        acc[ii] = __builtin_amdgcn_mfma_f32_16x16x32_bf16(a1, bC1, acc[ii], 0, 0, 0); \
        acc[ii] = __builtin_amdgcn_mfma_f32_16x16x32_bf16(a2, bC2, acc[ii], 0, 0, 0); \
        acc[ii] = __builtin_amdgcn_mfma_f32_16x16x32_bf16(a3, bC3, acc[ii], 0, 0, 0); }

    // vmcnt invariant: entering a body, in-flight = {L(ci), L(ci+1)} (+B if the
    // previous body was a pre-boundary: issued between its consume and its issue,
    // hence OLDER than L(ci+1)). vmcnt(1) leaves only L(ci+1): forces L(ci) and
    // any pending B -- exactly what this body consumes. Uniform vmcnt(1).
    #define BODY(PAR, XV, JV) { \
        int e  = wl[ci + PAR]; \
        int mt = __builtin_amdgcn_readfirstlane(e & 7); \
        int kT = e >> 3; \
        asm volatile("s_waitcnt vmcnt(1)" ::: "memory"); \
        if (isNew) { bC0 = bN0; bC1 = bN1; bC2 = bN2; bC3 = bN3; } \
        f32x4 xv = XV; \
        if (!(JV > 0)) xv = (f32x4){0.f, 0.f, 0.f, 0.f}; \
        uint32_t u0, u1; \
        asm("v_cvt_pk_bf16_f32 %0, %1, %2" : "=v"(u0) : "v"(xv.x), "v"(xv.y)); \
        asm("v_cvt_pk_bf16_f32 %0, %1, %2" : "=v"(u1) : "v"(xv.z), "v"(xv.w)); \
        { char* abw = PAR ? ab1 : ab0; *(u32x2*)(abw + wbyte) = (u32x2){u0, u1}; } \
        int eN = wl[ci + PAR + 1]; \
        bool nIsNew = (eN >> 3) != kT; \
        if (nIsNew) { int k2 = eN >> 3; bN0 = BLOAD(k2, 0); bN1 = BLOAD(k2, 1); bN2 = BLOAD(k2, 2); bN3 = BLOAD(k2, 3); } \
        { int e2 = wl[ci + PAR + 2]; int jv2 = jtabF[(e2 >> 3) * PB + (e2 & 7) * 16 + srow]; \
          JV = jv2; int j0 = jv2 > 0 ? jv2 - 1 : 0; \
          XV = *(const f32x4*)(x + (size_t)j0 * C + (sc4 << 2)); } \
        asm volatile("s_waitcnt lgkmcnt(0)" ::: "memory"); \
        __builtin_amdgcn_s_barrier(); \
        __builtin_amdgcn_sched_barrier(0); \
        const char* abr = PAR ? ab1 : ab0; \
        short8 a0 = *(const short8*)(abr + rb[0]); \
        short8 a1 = *(const short8*)(abr + rb[1]); \
        short8 a2 = *(const short8*)(abr + rb[2]); \
        short8 a3 = *(const short8*)(abr + rb[3]); \
        switch (mt) { \
            case 0: MFMA4(0); break; case 1: MFMA4(1); break; \
            case 2: MFMA4(2); break; case 3: MFMA4(3); break; \
            case 4: MFMA4(4); break; case 5: MFMA4(5); break; \
            case 6: MFMA4(6); break; case 7: MFMA4(7); break; \
        } \
        isNew = nIsNew; \
    }

    for (int ci = 0; ci < nc; ci += 2) {
        BODY(0, xvA, jA);
        BODY(1, xvB, jB);
    }
    #undef BODY
    #undef MFMA4
    #undef BLOAD

    __syncthreads();   // full drain (also retires the 2 dangling prefetches)

    // ---- LeakyReLU + LN partials (16-lane shfl reduce + LDS float atomics) ----
    #pragma unroll
    for (int m2 = 0; m2 < 8; ++m2) {
        #pragma unroll
        for (int rg = 0; rg < 4; ++rg) {
            float v = acc[m2][rg];
            v = (v >= 0.f) ? v : 0.2f * v;
            acc[m2][rg] = v;
            float s1 = v, s2 = v * v;
            s1 += __shfl_xor(s1, 1);  s2 += __shfl_xor(s2, 1);
            s1 += __shfl_xor(s1, 2);  s2 += __shfl_xor(s2, 2);
            s1 += __shfl_xor(s1, 4);  s2 += __shfl_xor(s2, 4);
            s1 += __shfl_xor(s1, 8);  s2 += __shfl_xor(s2, 8);
            if (arow == 0) {
                int row = (m2 << 4) + (kgrp << 2) + rg;
                atomicAdd(&p1s[row], s1);
                atomicAdd(&p2s[row], s2);
            }
        }
    }
    __syncthreads();
    if (tid < PB) {
        float s1 = p1s[tid], s2 = p2s[tid];
        float mean = s1 * (1.f / 128.f);
        float var  = s2 * (1.f / 128.f) - mean * mean;
        mr[tid] = make_float2(mean, rsqrtf(var + 1e-5f));
    }
    __syncthreads();

    // ---- normalize + write ----
    float gm = gamma[(w << 4) + arow], bt = beta[(w << 4) + arow];
    #pragma unroll
    for (int m2 = 0; m2 < 8; ++m2) {
        #pragma unroll
        for (int rg = 0; rg < 4; ++rg) {
            int row = (m2 << 4) + (kgrp << 2) + rg;
            int gp  = base + row;
            if (gp < n) {
                float2 mm = mr[row];
                out[(size_t)gp * C + (w << 4) + arow] = (acc[m2][rg] - mm.x) * mm.y * gm + bt;
            }
        }
    }
}

// ---------------- host launcher ----------------

extern "C" void kernel_launch(void* const* d_in, const int* in_sizes, int n_in,
                              void* d_out, int out_size, void* d_ws, size_t ws_size,
                              hipStream_t stream) {
    const int*   pts   = (const int*)d_in[1];
    const float* x     = (const float*)d_in[5];
    const float* w     = (const float*)d_in[7];
    const float* bias  = (const float*)d_in[8];
    const float* gamma = (const float*)d_in[9];
    const float* beta  = (const float*)d_in[10];
    float*       out   = (float*)d_out;

    int n     = in_sizes[1] / 3;
    int level = in_sizes[3] / 2 - 2;     // pyramids: 2*(level+2) elems
    int r     = 1 << level;
    size_t r3 = (size_t)r * r * r;

    char* wsb = (char*)d_ws;
    uint32_t* wpf = (uint32_t*)wsb;
    size_t wp_bytes = (((size_t)TOTAL_W * 4) + 255) & ~(size_t)255;
    int* codes = (int*)(wsb + wp_bytes);
    size_t codes_bytes = ((size_t)n * 4 + 255) & ~(size_t)255;
    int* table = (int*)(wsb + wp_bytes + codes_bytes);
    bool use_table = ws_size >= wp_bytes + codes_bytes + r3 * 4;

    int nb = (n + PB - 1) / PB;
    if (use_table) {
        int tot = TOTAL_W + n;
        k_prep<<<(tot + 255) / 256, 256, 0, stream>>>(w, wpf, pts, table, n, r);
        k_main<true><<<nb, 512, 0, stream>>>(pts, x, wpf, bias, gamma, beta,
                                             table, codes, out, n, r, nb);
    } else {
        k_prep<<<(TOTAL_W + 255) / 256, 256, 0, stream>>>(w, wpf, pts, table, 0, r);
        k_codes<<<(n + 255) / 256, 256, 0, stream>>>(pts, codes, n, r);
        k_main<false><<<nb, 512, 0, stream>>>(pts, x, wpf, bias, gamma, beta,
                                              table, codes, out, n, r, nb);
    }
}